// Round 1
// baseline (86.759 us; speedup 1.0000x reference)
//
#include <hip/hip_runtime.h>

#define HW 256   // h*w = 16*16
#define C  128   // channels (= d = o = p)

// Block-wide reduction of 4 floats across 256 threads (4 waves of 64).
// Results are broadcast to all threads.
__device__ __forceinline__ void blockReduce4(float& a, float& b, float& c, float& d,
                                             float (*sm)[4]) {
    #pragma unroll
    for (int off = 32; off > 0; off >>= 1) {
        a += __shfl_down(a, off, 64);
        b += __shfl_down(b, off, 64);
        c += __shfl_down(c, off, 64);
        d += __shfl_down(d, off, 64);
    }
    const int wid  = threadIdx.x >> 6;
    const int lane = threadIdx.x & 63;
    if (lane == 0) { sm[wid][0] = a; sm[wid][1] = b; sm[wid][2] = c; sm[wid][3] = d; }
    __syncthreads();
    a = sm[0][0] + sm[1][0] + sm[2][0] + sm[3][0];
    b = sm[0][1] + sm[1][1] + sm[2][1] + sm[3][1];
    c = sm[0][2] + sm[1][2] + sm[2][2] + sm[3][2];
    d = sm[0][3] + sm[1][3] + sm[2][3] + sm[3][3];
}

// Kernel 1: instance-norm + relu of x (with pos add) and y.
// grid = 512 blocks: blk<256 -> x (bc = b*128+c), blk>=256 -> y.
__global__ __launch_bounds__(256) void k_norm(
        const float* __restrict__ x, const float* __restrict__ y,
        const float* __restrict__ pos, float* __restrict__ xn, float* __restrict__ yn) {
    __shared__ float sm[4][4];
    const int blk = blockIdx.x;
    const int tid = threadIdx.x;   // spatial index j in [0,256)
    float v;
    float* dst;
    if (blk < 256) {
        const int c = blk & 127;
        // pos[c][j] = pos_emb[j][c]
        v = x[blk * HW + tid] + pos[tid * C + c];
        dst = xn + blk * HW;
    } else {
        const int bc = blk - 256;
        v = y[bc * HW + tid];
        dst = yn + bc * HW;
    }
    float s = v, s2 = v * v, z3 = 0.0f, z4 = 0.0f;
    blockReduce4(s, s2, z3, z4, sm);
    const float m    = s  * (1.0f / 256.0f);
    const float var  = s2 * (1.0f / 256.0f) - m * m;
    const float r    = (v - m) * rsqrtf(var + 1e-5f);
    dst[tid] = r > 0.0f ? r : 0.0f;
}

// Kernel 2: per (b,o): A_j, B_i, fused instance-norm stats of z = A_j + B_i + b1
// (b1 cancels under the norm), relu + sum over j -> s[b,o,i].
// grid = 256 blocks (b*128+o), 256 threads (i / j).
__global__ __launch_bounds__(256) void k_rel(
        const float* __restrict__ xn, const float* __restrict__ yn,
        const float* __restrict__ w1, float* __restrict__ s_out) {
    __shared__ float sm[4][4];
    __shared__ float wrow[384];
    __shared__ float sha[256];
    const int bo = blockIdx.x;
    const int b  = bo >> 7;
    const int o  = bo & 127;
    const int i  = threadIdx.x;

    if (i < 128) {
        wrow[i]       = w1[o * 384 + i];          // Wi row
        wrow[128 + i] = w1[o * 384 + 128 + i];    // Wj row
        wrow[256 + i] = w1[o * 384 + 256 + i];    // Wy row
    }
    __syncthreads();

    const float* xb = xn + b * (C * HW);
    const float* yb = yn + b * (C * HW);

    float A = 0.0f, Bv = 0.0f;
    #pragma unroll 8
    for (int c = 0; c < 128; ++c) {
        const float xv = xb[c * HW + i];          // coalesced across threads
        A  = fmaf(wrow[c],       xv, A);
        Bv = fmaf(wrow[128 + c], xv, Bv);
    }
    #pragma unroll 8
    for (int d2 = 0; d2 < 128; ++d2) {
        const float yv = yb[d2 * HW + i];
        Bv = fmaf(wrow[256 + d2], yv, Bv);
    }

    float sA = A, sA2 = A * A, sB = Bv, sB2 = Bv * Bv;
    blockReduce4(sA, sA2, sB, sB2, sm);

    const float mA   = sA  * (1.0f / 256.0f);
    const float mB   = sB  * (1.0f / 256.0f);
    const float varA = sA2 * (1.0f / 256.0f) - mA * mA;
    const float varB = sB2 * (1.0f / 256.0f) - mB * mB;
    const float istd = rsqrtf(varA + varB + 1e-5f);

    sha[i] = (A - mA) * istd;                     // a_j (this thread's j == i)
    const float bb = (Bv - mB) * istd;            // b_i
    __syncthreads();

    float acc = 0.0f;
    #pragma unroll 8
    for (int j = 0; j < 256; ++j) {
        const float t = sha[j] + bb;              // LDS broadcast read
        acc += (t > 0.0f ? t : 0.0f);
    }
    s_out[bo * HW + i] = acc;
}

// Kernel 3: out[b,p,i] = sum_o w2[p,o] * s[b,o,i] + 256*b2[p]
__global__ __launch_bounds__(256) void k_out(
        const float* __restrict__ s_in, const float* __restrict__ w2,
        const float* __restrict__ b2, float* __restrict__ out) {
    __shared__ float wrow[128];
    const int bp = blockIdx.x;
    const int b  = bp >> 7;
    const int p  = bp & 127;
    const int i  = threadIdx.x;
    if (i < 128) wrow[i] = w2[p * 128 + i];
    __syncthreads();
    const float* sb = s_in + b * (C * HW);
    float acc = 256.0f * b2[p];
    #pragma unroll 8
    for (int o = 0; o < 128; ++o)
        acc = fmaf(wrow[o], sb[o * HW + i], acc);
    out[bp * HW + i] = acc;
}

extern "C" void kernel_launch(void* const* d_in, const int* in_sizes, int n_in,
                              void* d_out, int out_size, void* d_ws, size_t ws_size,
                              hipStream_t stream) {
    const float* x   = (const float*)d_in[0];   // (2,128,16,16)
    const float* y   = (const float*)d_in[1];   // (2,128,16,16)
    const float* pos = (const float*)d_in[2];   // (256,128)
    const float* w1  = (const float*)d_in[3];   // (128,384)
    // d_in[4] = b1: provably cancelled by the z instance-norm -> unused.
    const float* w2  = (const float*)d_in[5];   // (128,128)
    const float* b2  = (const float*)d_in[6];   // (128,)
    float* out = (float*)d_out;                 // (2,128,16,16) flat = 65536

    float* xn = (float*)d_ws;        // 65536 f32
    float* yn = xn + 65536;          // 65536 f32
    float* s  = yn + 65536;          // 65536 f32

    k_norm<<<512, 256, 0, stream>>>(x, y, pos, xn, yn);
    k_rel <<<256, 256, 0, stream>>>(xn, yn, w1, s);
    k_out <<<256, 256, 0, stream>>>(s, w2, b2, out);
}

// Round 3
// 77.754 us; speedup vs baseline: 1.1158x; 1.1158x over previous
//
#include <hip/hip_runtime.h>

#define HW 256   // h*w = 16*16
#define C  128   // channels (= d = o = p)

// ---- block reduction helpers -------------------------------------------
// Reduce 4 floats across NW waves (blockDim = NW*64), broadcast to all.
template<int NW>
__device__ __forceinline__ void blockReduce4(float& a, float& b, float& c, float& d,
                                             float (*sm)[4]) {
    #pragma unroll
    for (int off = 32; off > 0; off >>= 1) {
        a += __shfl_xor(a, off, 64);
        b += __shfl_xor(b, off, 64);
        c += __shfl_xor(c, off, 64);
        d += __shfl_xor(d, off, 64);
    }
    const int wid  = threadIdx.x >> 6;
    const int lane = threadIdx.x & 63;
    if (lane == 0) { sm[wid][0] = a; sm[wid][1] = b; sm[wid][2] = c; sm[wid][3] = d; }
    __syncthreads();
    a = 0.f; b = 0.f; c = 0.f; d = 0.f;
    #pragma unroll
    for (int w = 0; w < NW; ++w) {
        a += sm[w][0]; b += sm[w][1]; c += sm[w][2]; d += sm[w][3];
    }
    __syncthreads();   // sm reusable afterwards
}

// ---- Kernel 1: instance-norm + relu of x (with pos add) and y ----------
// grid = 512: blk<256 -> x channel (b*128+c), blk>=256 -> y channel.
__global__ __launch_bounds__(256) void k_norm(
        const float* __restrict__ x, const float* __restrict__ y,
        const float* __restrict__ pos, float* __restrict__ xn, float* __restrict__ yn) {
    __shared__ float sm[4][4];
    const int blk = blockIdx.x;
    const int tid = threadIdx.x;   // spatial index j
    float v;
    float* dst;
    if (blk < 256) {
        const int c = blk & 127;
        v = x[blk * HW + tid] + pos[tid * C + c];   // pos[c][j] = pos_emb[j][c]
        dst = xn + blk * HW;
    } else {
        const int bc = blk - 256;
        v = y[bc * HW + tid];
        dst = yn + bc * HW;
    }
    float s = v, s2 = v * v, z3 = 0.f, z4 = 0.f;
    blockReduce4<4>(s, s2, z3, z4, sm);
    const float m   = s  * (1.0f / 256.0f);
    const float var = s2 * (1.0f / 256.0f) - m * m;
    const float r   = (v - m) * rsqrtf(var + 1e-5f);
    dst[tid] = r > 0.0f ? r : 0.0f;
}

// ---- Kernel 2: per (b,o) fused A/B GEMV + z-norm + relu-sum ------------
// z[b,o,i,j] = A[j] + B[i] + b1[o]; b1 cancels under the instance norm;
// mean(z) = Ā+B̄, var(z) = var(A)+var(B). s[b,o,i] = Σ_j relu(a_j + b_i).
// grid = 256 (b*128+o), 1024 threads: quarter q = t>>8 splits both the
// channel loop (32 c each) and the j loop (64 j each).
__global__ __launch_bounds__(1024) void k_rel(
        const float* __restrict__ xn, const float* __restrict__ yn,
        const float* __restrict__ w1, float* __restrict__ s_out) {
    __shared__ float pA[4][256];
    __shared__ float pB[4][256];
    __shared__ float red[16][4];
    __shared__ float aj[256];
    __shared__ float bi[256];
    __shared__ float wrow[384];

    const int t  = threadIdx.x;
    const int i  = t & 255;
    const int q  = t >> 8;
    const int bo = blockIdx.x;
    const int b  = bo >> 7;
    const int o  = bo & 127;

    if (t < 384) wrow[t] = w1[o * 384 + t];
    __syncthreads();

    const float* xb = xn + b * (C * HW);
    const float* yb = yn + b * (C * HW);

    // quarter of the channel dot products, fully unrolled (64 loads in flight)
    float A = 0.f, Bv = 0.f;
    const int c0 = q * 32;
    #pragma unroll
    for (int cc = 0; cc < 32; ++cc) {
        const int c = c0 + cc;
        const float xv = xb[c * HW + i];
        A  = fmaf(wrow[c],       xv, A);
        Bv = fmaf(wrow[128 + c], xv, Bv);
        const float yv = yb[c * HW + i];
        Bv = fmaf(wrow[256 + c], yv, Bv);
    }
    pA[q][i] = A;
    pB[q][i] = Bv;
    __syncthreads();

    // combine quarters on t<256, then block-wide moment reduction
    float Af = 0.f, Bf = 0.f;
    if (t < 256) {
        Af = pA[0][i] + pA[1][i] + pA[2][i] + pA[3][i];
        Bf = pB[0][i] + pB[1][i] + pB[2][i] + pB[3][i];
    }
    float sA = Af, sA2 = Af * Af, sB = Bf, sB2 = Bf * Bf;
    blockReduce4<16>(sA, sA2, sB, sB2, red);

    const float mA   = sA  * (1.0f / 256.0f);
    const float mB   = sB  * (1.0f / 256.0f);
    const float varA = sA2 * (1.0f / 256.0f) - mA * mA;
    const float varB = sB2 * (1.0f / 256.0f) - mB * mB;
    const float istd = rsqrtf(varA + varB + 1e-5f);

    if (t < 256) {
        aj[i] = (Af - mA) * istd;
        bi[i] = (Bf - mB) * istd;
    }
    __syncthreads();

    // quarter of the relu-sum over j
    const float bb = bi[i];
    float acc = 0.f;
    const int j0 = q * 64;
    #pragma unroll
    for (int jj = 0; jj < 64; ++jj) {
        const float v = aj[j0 + jj] + bb;   // LDS broadcast within wave
        acc += (v > 0.f ? v : 0.f);
    }
    pA[q][i] = acc;
    __syncthreads();
    if (t < 256)
        s_out[bo * HW + i] = pA[0][i] + pA[1][i] + pA[2][i] + pA[3][i];
}

// ---- Kernel 3: out[b,p,i] = Σ_o w2[p,o]·s[b,o,i] + 256·b2[p] -----------
// grid = 256 (b*128+p), 1024 threads, quarter-split over o.
__global__ __launch_bounds__(1024) void k_out(
        const float* __restrict__ s_in, const float* __restrict__ w2,
        const float* __restrict__ b2, float* __restrict__ out) {
    __shared__ float wrow[128];
    __shared__ float pacc[4][256];
    const int t  = threadIdx.x;
    const int i  = t & 255;
    const int q  = t >> 8;
    const int bp = blockIdx.x;
    const int b  = bp >> 7;
    const int p  = bp & 127;
    if (t < 128) wrow[t] = w2[p * 128 + t];
    __syncthreads();
    const float* sb = s_in + b * (C * HW);
    float acc = 0.f;
    const int o0 = q * 32;
    #pragma unroll
    for (int oo = 0; oo < 32; ++oo)
        acc = fmaf(wrow[o0 + oo], sb[(o0 + oo) * HW + i], acc);
    pacc[q][i] = acc;
    __syncthreads();
    if (t < 256)
        out[bp * HW + i] = pacc[0][i] + pacc[1][i] + pacc[2][i] + pacc[3][i]
                           + 256.0f * b2[p];
}

extern "C" void kernel_launch(void* const* d_in, const int* in_sizes, int n_in,
                              void* d_out, int out_size, void* d_ws, size_t ws_size,
                              hipStream_t stream) {
    const float* x   = (const float*)d_in[0];   // (2,128,16,16)
    const float* y   = (const float*)d_in[1];   // (2,128,16,16)
    const float* pos = (const float*)d_in[2];   // (256,128)
    const float* w1  = (const float*)d_in[3];   // (128,384)
    // d_in[4] = b1: cancelled by the z instance-norm -> unused.
    const float* w2  = (const float*)d_in[5];   // (128,128)
    const float* b2  = (const float*)d_in[6];   // (128,)
    float* out = (float*)d_out;                 // (2,128,16,16) flat = 65536

    float* xn = (float*)d_ws;        // 65536 f32
    float* yn = xn + 65536;          // 65536 f32
    float* s  = yn + 65536;          // 65536 f32

    k_norm<<<512, 256, 0, stream>>>(x, y, pos, xn, yn);
    k_rel <<<256, 1024, 0, stream>>>(xn, yn, w1, s);
    k_out <<<256, 1024, 0, stream>>>(s, w2, b2, out);
}